// Round 2
// baseline (1349.098 us; speedup 1.0000x reference)
//
#include <hip/hip_runtime.h>
#include <cstdint>
#include <cstddef>

// ---------------------------------------------------------------------------
// GCN 3-layer + FC head. Round 2: int32 edge_index, aggregate-first + fused
// GEMM  h = lrelu(SX@gw + x@lw + (gb+lb)),  ws ~59.7 MB.
// ---------------------------------------------------------------------------

__global__ __launch_bounds__(256) void k_init_deg(int* __restrict__ deg, int n) {
  int i = blockIdx.x * 256 + threadIdx.x;
  if (i < n) deg[i] = 1;              // self-loop contributes 1 to every node
}

__global__ __launch_bounds__(256) void k_count(const int* __restrict__ ei,
                                               int* __restrict__ deg, int E) {
  int e = blockIdx.x * 256 + threadIdx.x;
  if (e < E) atomicAdd(&deg[ei[E + e]], 1);   // dst half
}

// one-block exclusive scan of deg -> rowptr (and a copy into fillctr)
__global__ __launch_bounds__(1024) void k_scan(const int* __restrict__ deg,
                                               int* __restrict__ rowptr,
                                               int* __restrict__ fillctr,
                                               int n, int total) {
  __shared__ int sums[1024];
  int t = threadIdx.x;
  int chunk = (n + 1023) >> 10;
  int beg = t * chunk;
  int end = min(beg + chunk, n);
  int s = 0;
  for (int i = beg; i < end; ++i) s += deg[i];
  sums[t] = s;
  __syncthreads();
  for (int off = 1; off < 1024; off <<= 1) {
    int v = (t >= off) ? sums[t - off] : 0;
    __syncthreads();
    sums[t] += v;
    __syncthreads();
  }
  int run = (t == 0) ? 0 : sums[t - 1];
  for (int i = beg; i < end; ++i) {
    rowptr[i] = run;
    fillctr[i] = run;
    run += deg[i];
  }
  if (t == 0) rowptr[n] = total;
}

__global__ __launch_bounds__(256) void k_dis(const int* __restrict__ deg,
                                             float* __restrict__ dis, int n) {
  int i = blockIdx.x * 256 + threadIdx.x;
  if (i < n) dis[i] = rsqrtf((float)deg[i]);   // deg >= 1 always
}

__global__ __launch_bounds__(256) void k_fill(const int* __restrict__ ei,
                                              int* __restrict__ fillctr,
                                              int* __restrict__ col,
                                              int E, int n) {
  int e = blockIdx.x * 256 + threadIdx.x;
  int total = E + n;
  if (e >= total) return;
  int s, d;
  if (e < E) {
    s = ei[e];
    d = ei[E + e];
  } else {
    s = e - E;  // self-loop
    d = s;
  }
  int pos = atomicAdd(&fillctr[d], 1);
  col[pos] = s;
}

// ---------------------------------------------------------------------------
// SX[i] = dis[i] * sum_{j in CSR row i} dis[col[j]] * Xin[col[j], :]
// one wave per node, float2 per lane (128 features / 64 lanes).
// ---------------------------------------------------------------------------
__global__ __launch_bounds__(256) void k_spmv(const int* __restrict__ rowptr,
                                              const int* __restrict__ col,
                                              const float* __restrict__ dis,
                                              const float* __restrict__ Xin,
                                              float* __restrict__ SX, int n) {
  const int wave = threadIdx.x >> 6;
  const int lane = threadIdx.x & 63;
  const int i = blockIdx.x * 4 + wave;
  if (i >= n) return;
  const int beg = rowptr[i];
  const int end = rowptr[i + 1];
  float2 acc = make_float2(0.f, 0.f);
  for (int j = beg; j < end; ++j) {
    int c = col[j];
    float wv = dis[c];
    float2 xv = *(const float2*)(Xin + (size_t)c * 128 + lane * 2);
    acc.x = fmaf(xv.x, wv, acc.x);
    acc.y = fmaf(xv.y, wv, acc.y);
  }
  float di = dis[i];
  acc.x *= di;
  acc.y *= di;
  *(float2*)(SX + (size_t)i * 128 + lane * 2) = acc;
}

// ---------------------------------------------------------------------------
// Fused GCN layer GEMM:  out = lrelu( inA@Wa + inB@Wb + (ba+bb) )
// inA = SX [M,128], inB = h_prev [M,128]. out may alias inB (block reads all
// its input rows before its post-loop stores; row ranges disjoint per block).
// 128x128 tile, BK=8, 256 threads, 8x8 acc per thread.
// ---------------------------------------------------------------------------
#define BM 128

__global__ __launch_bounds__(256) void k_gemm2(const float* __restrict__ inA,
                                               const float* __restrict__ inB,
                                               const float* __restrict__ Wa,
                                               const float* __restrict__ Wb,
                                               const float* __restrict__ ba,
                                               const float* __restrict__ bb,
                                               float* __restrict__ out, int M) {
  __shared__ float As[8][BM];
  __shared__ float Bs[8][BM];
  const int tid = threadIdx.x;
  const int row0 = blockIdx.x * BM;
  const int tx = tid & 15;
  const int ty = tid >> 4;
  const int ar = tid >> 1;            // 0..127 row in tile
  const int ag = (tid & 1) * 4;       // k group base (0 or 4)
  const int bk = tid >> 5;            // 0..7 k row
  const int bg = (tid & 31) * 4;      // col group base

  float acc[8][8];
#pragma unroll
  for (int i = 0; i < 8; ++i)
#pragma unroll
    for (int j = 0; j < 8; ++j) acc[i][j] = 0.f;

#pragma unroll
  for (int p = 0; p < 2; ++p) {
    const float* src = p ? inB : inA;
    const float* W = p ? Wb : Wa;
    for (int k0 = 0; k0 < 128; k0 += 8) {
      float4 av = make_float4(0.f, 0.f, 0.f, 0.f);
      if (row0 + ar < M)
        av = *(const float4*)(src + (size_t)(row0 + ar) * 128 + k0 + ag);
      float4 bv = *(const float4*)(W + (size_t)(k0 + bk) * 128 + bg);
      __syncthreads();
      As[ag + 0][ar] = av.x;
      As[ag + 1][ar] = av.y;
      As[ag + 2][ar] = av.z;
      As[ag + 3][ar] = av.w;
      *(float4*)(&Bs[bk][bg]) = bv;
      __syncthreads();
#pragma unroll
      for (int k = 0; k < 8; ++k) {
        float a[8], b[8];
        *(float4*)(a)     = *(const float4*)(&As[k][ty * 8]);
        *(float4*)(a + 4) = *(const float4*)(&As[k][ty * 8 + 4]);
        *(float4*)(b)     = *(const float4*)(&Bs[k][tx * 8]);
        *(float4*)(b + 4) = *(const float4*)(&Bs[k][tx * 8 + 4]);
#pragma unroll
        for (int i = 0; i < 8; ++i)
#pragma unroll
          for (int j = 0; j < 8; ++j) acc[i][j] = fmaf(a[i], b[j], acc[i][j]);
      }
    }
  }

#pragma unroll
  for (int i = 0; i < 8; ++i) {
    int r = row0 + ty * 8 + i;
    if (r >= M) continue;
    float* dstp = out + (size_t)r * 128;
#pragma unroll
    for (int jv = 0; jv < 2; ++jv) {
      int c = tx * 8 + jv * 4;
      float4 v;
      v.x = acc[i][jv * 4 + 0] + ba[c + 0] + bb[c + 0];
      v.y = acc[i][jv * 4 + 1] + ba[c + 1] + bb[c + 1];
      v.z = acc[i][jv * 4 + 2] + ba[c + 2] + bb[c + 2];
      v.w = acc[i][jv * 4 + 3] + ba[c + 3] + bb[c + 3];
      v.x = (v.x > 0.f) ? v.x : 0.01f * v.x;
      v.y = (v.y > 0.f) ? v.y : 0.01f * v.y;
      v.z = (v.z > 0.f) ? v.z : 0.01f * v.z;
      v.w = (v.w > 0.f) ? v.w : 0.01f * v.w;
      *(float4*)(dstp + c) = v;
    }
  }
}

// ---------------------------------------------------------------------------
// FC head: y = h @ fcw + fcb   ([N,128]x[128,64]); one wave per row.
// ---------------------------------------------------------------------------
__global__ __launch_bounds__(256) void k_fc(const float* __restrict__ h,
                                            const float* __restrict__ fcw,
                                            const float* __restrict__ fcb,
                                            float* __restrict__ y, int n) {
  __shared__ float ws[128 * 64];
  for (int t = threadIdx.x; t < 128 * 64; t += 256) ws[t] = fcw[t];
  __syncthreads();
  const int wave = threadIdx.x >> 6;
  const int lane = threadIdx.x & 63;
  const int i = blockIdx.x * 4 + wave;
  if (i >= n) return;
  const float* hr = h + (size_t)i * 128;
  float acc = fcb[lane];
#pragma unroll 8
  for (int k4 = 0; k4 < 32; ++k4) {
    float4 hv = *(const float4*)(hr + k4 * 4);
    acc = fmaf(hv.x, ws[(k4 * 4 + 0) * 64 + lane], acc);
    acc = fmaf(hv.y, ws[(k4 * 4 + 1) * 64 + lane], acc);
    acc = fmaf(hv.z, ws[(k4 * 4 + 2) * 64 + lane], acc);
    acc = fmaf(hv.w, ws[(k4 * 4 + 3) * 64 + lane], acc);
  }
  y[(size_t)i * 64 + lane] = acc;
}

// ---------------------------------------------------------------------------

extern "C" void kernel_launch(void* const* d_in, const int* in_sizes, int n_in,
                              void* d_out, int out_size, void* d_ws, size_t ws_size,
                              hipStream_t stream) {
  const float* X  = (const float*)d_in[0];
  const int* ei   = (const int*)d_in[1];       // int32 per harness convention
  const float* gw1 = (const float*)d_in[3];
  const float* gb1 = (const float*)d_in[4];
  const float* lw1 = (const float*)d_in[5];
  const float* lb1 = (const float*)d_in[6];
  const float* gw2 = (const float*)d_in[7];
  const float* gb2 = (const float*)d_in[8];
  const float* lw2 = (const float*)d_in[9];
  const float* lb2 = (const float*)d_in[10];
  const float* gw3 = (const float*)d_in[11];
  const float* gb3 = (const float*)d_in[12];
  const float* lw3 = (const float*)d_in[13];
  const float* lb3 = (const float*)d_in[14];
  const float* fcw = (const float*)d_in[15];
  const float* fcb = (const float*)d_in[16];

  const int n = in_sizes[0] / 128;
  const int E = in_sizes[1] / 2;
  const int tot = E + n;

  char* ws = (char*)d_ws;
  size_t off = 0;
  auto alloc = [&](size_t bytes) -> void* {
    void* p = ws + off;
    off = (off + bytes + 255) & ~(size_t)255;
    return p;
  };
  int* deg     = (int*)alloc((size_t)n * 4);
  float* dis   = (float*)alloc((size_t)n * 4);
  int* rowptr  = (int*)alloc((size_t)(n + 1) * 4);
  int* fillctr = (int*)alloc((size_t)n * 4);
  int* col     = (int*)alloc((size_t)tot * 4);
  float* SX    = (float*)alloc((size_t)n * 128 * 4);   // total ~59.7 MB

  float* outh = (float*)d_out;                 // [n,128] final h (also h ping)
  float* outy = outh + (size_t)n * 128;        // [n,64]  final y

  const int gN = (n + 255) / 256;
  const int gE = (E + 255) / 256;
  const int gT = (tot + 255) / 256;
  const int gM = (n + BM - 1) / BM;
  const int gW = (n + 3) / 4;

  // ---- graph preprocessing (deterministic; rebuilt every call) ----
  k_init_deg<<<gN, 256, 0, stream>>>(deg, n);
  k_count<<<gE, 256, 0, stream>>>(ei, deg, E);
  k_scan<<<1, 1024, 0, stream>>>(deg, rowptr, fillctr, n, tot);
  k_dis<<<gN, 256, 0, stream>>>(deg, dis, n);
  k_fill<<<gT, 256, 0, stream>>>(ei, fillctr, col, E, n);

  // ---- layer 1: SX = S@X ; h1 = lrelu(SX@gw1 + X@lw1 + b) -> outh ----
  k_spmv<<<gW, 256, 0, stream>>>(rowptr, col, dis, X, SX, n);
  k_gemm2<<<gM, 256, 0, stream>>>(SX, X, gw1, lw1, gb1, lb1, outh, n);
  // ---- layer 2 (in-place on outh) ----
  k_spmv<<<gW, 256, 0, stream>>>(rowptr, col, dis, outh, SX, n);
  k_gemm2<<<gM, 256, 0, stream>>>(SX, outh, gw2, lw2, gb2, lb2, outh, n);
  // ---- layer 3 (in-place on outh) ----
  k_spmv<<<gW, 256, 0, stream>>>(rowptr, col, dis, outh, SX, n);
  k_gemm2<<<gM, 256, 0, stream>>>(SX, outh, gw3, lw3, gb3, lb3, outh, n);
  // ---- FC head ----
  k_fc<<<gW, 256, 0, stream>>>(outh, fcw, fcb, outy, n);
}

// Round 3
// 1126.044 us; speedup vs baseline: 1.1981x; 1.1981x over previous
//
#include <hip/hip_runtime.h>
#include <cstdint>
#include <cstddef>

// ---------------------------------------------------------------------------
// GCN 3-layer + FC head. Round 3: hierarchical scan (kills the 230us
// single-block scan), dis fused into scan-write. Rest unchanged.
// ---------------------------------------------------------------------------

__global__ __launch_bounds__(256) void k_init_deg(int* __restrict__ deg, int n) {
  int i = blockIdx.x * 256 + threadIdx.x;
  if (i < n) deg[i] = 1;              // self-loop contributes 1 to every node
}

__global__ __launch_bounds__(256) void k_count(const int* __restrict__ ei,
                                               int* __restrict__ deg, int E) {
  int e = blockIdx.x * 256 + threadIdx.x;
  if (e < E) atomicAdd(&deg[ei[E + e]], 1);   // dst half
}

// ---- hierarchical exclusive scan of deg over n elements ----
// pass 1: per-block (256-elem) sums
__global__ __launch_bounds__(256) void k_partial(const int* __restrict__ deg,
                                                 int* __restrict__ partial, int n) {
  __shared__ int sm[256];
  int t = threadIdx.x;
  int i = blockIdx.x * 256 + t;
  sm[t] = (i < n) ? deg[i] : 0;
  __syncthreads();
#pragma unroll
  for (int off = 128; off > 0; off >>= 1) {
    if (t < off) sm[t] += sm[t + off];
    __syncthreads();
  }
  if (t == 0) partial[blockIdx.x] = sm[0];
}

// pass 2: one block scans the (<=512) partials -> exclusive block offsets
__global__ __launch_bounds__(512) void k_scanp(const int* __restrict__ partial,
                                               int* __restrict__ poff, int nb,
                                               int* __restrict__ rowptr, int n,
                                               int total) {
  __shared__ int sm[512];
  int t = threadIdx.x;
  sm[t] = (t < nb) ? partial[t] : 0;
  __syncthreads();
  for (int off = 1; off < 512; off <<= 1) {
    int v = (t >= off) ? sm[t - off] : 0;
    __syncthreads();
    sm[t] += v;
    __syncthreads();
  }
  if (t < nb) poff[t] = (t == 0) ? 0 : sm[t - 1];
  if (t == 0) rowptr[n] = total;
}

// pass 3: per-block rescan + write rowptr/fillctr, fused dis = rsqrt(deg)
__global__ __launch_bounds__(256) void k_write(const int* __restrict__ deg,
                                               const int* __restrict__ poff,
                                               int* __restrict__ rowptr,
                                               int* __restrict__ fillctr,
                                               float* __restrict__ dis, int n) {
  __shared__ int sm[256];
  int t = threadIdx.x;
  int i = blockIdx.x * 256 + t;
  int v = (i < n) ? deg[i] : 0;
  sm[t] = v;
  __syncthreads();
  for (int off = 1; off < 256; off <<= 1) {
    int u = (t >= off) ? sm[t - off] : 0;
    __syncthreads();
    sm[t] += u;
    __syncthreads();
  }
  if (i < n) {
    int excl = poff[blockIdx.x] + sm[t] - v;
    rowptr[i] = excl;
    fillctr[i] = excl;
    dis[i] = rsqrtf((float)v);        // deg >= 1 always
  }
}

__global__ __launch_bounds__(256) void k_fill(const int* __restrict__ ei,
                                              int* __restrict__ fillctr,
                                              int* __restrict__ col,
                                              int E, int n) {
  int e = blockIdx.x * 256 + threadIdx.x;
  int total = E + n;
  if (e >= total) return;
  int s, d;
  if (e < E) {
    s = ei[e];
    d = ei[E + e];
  } else {
    s = e - E;  // self-loop
    d = s;
  }
  int pos = atomicAdd(&fillctr[d], 1);
  col[pos] = s;
}

// ---------------------------------------------------------------------------
// SX[i] = dis[i] * sum_{j in CSR row i} dis[col[j]] * Xin[col[j], :]
// one wave per node, float2 per lane (128 features / 64 lanes).
// ---------------------------------------------------------------------------
__global__ __launch_bounds__(256) void k_spmv(const int* __restrict__ rowptr,
                                              const int* __restrict__ col,
                                              const float* __restrict__ dis,
                                              const float* __restrict__ Xin,
                                              float* __restrict__ SX, int n) {
  const int wave = threadIdx.x >> 6;
  const int lane = threadIdx.x & 63;
  const int i = blockIdx.x * 4 + wave;
  if (i >= n) return;
  const int beg = rowptr[i];
  const int end = rowptr[i + 1];
  float2 acc = make_float2(0.f, 0.f);
  for (int j = beg; j < end; ++j) {
    int c = col[j];
    float wv = dis[c];
    float2 xv = *(const float2*)(Xin + (size_t)c * 128 + lane * 2);
    acc.x = fmaf(xv.x, wv, acc.x);
    acc.y = fmaf(xv.y, wv, acc.y);
  }
  float di = dis[i];
  acc.x *= di;
  acc.y *= di;
  *(float2*)(SX + (size_t)i * 128 + lane * 2) = acc;
}

// ---------------------------------------------------------------------------
// Fused GCN layer GEMM:  out = lrelu( inA@Wa + inB@Wb + (ba+bb) )
// 128x128 tile, BK=8, 256 threads, 8x8 acc per thread. out may alias inB.
// ---------------------------------------------------------------------------
#define BM 128

__global__ __launch_bounds__(256) void k_gemm2(const float* __restrict__ inA,
                                               const float* __restrict__ inB,
                                               const float* __restrict__ Wa,
                                               const float* __restrict__ Wb,
                                               const float* __restrict__ ba,
                                               const float* __restrict__ bb,
                                               float* __restrict__ out, int M) {
  __shared__ float As[8][BM];
  __shared__ float Bs[8][BM];
  const int tid = threadIdx.x;
  const int row0 = blockIdx.x * BM;
  const int tx = tid & 15;
  const int ty = tid >> 4;
  const int ar = tid >> 1;            // 0..127 row in tile
  const int ag = (tid & 1) * 4;       // k group base (0 or 4)
  const int bk = tid >> 5;            // 0..7 k row
  const int bg = (tid & 31) * 4;      // col group base

  float acc[8][8];
#pragma unroll
  for (int i = 0; i < 8; ++i)
#pragma unroll
    for (int j = 0; j < 8; ++j) acc[i][j] = 0.f;

#pragma unroll
  for (int p = 0; p < 2; ++p) {
    const float* src = p ? inB : inA;
    const float* W = p ? Wb : Wa;
    for (int k0 = 0; k0 < 128; k0 += 8) {
      float4 av = make_float4(0.f, 0.f, 0.f, 0.f);
      if (row0 + ar < M)
        av = *(const float4*)(src + (size_t)(row0 + ar) * 128 + k0 + ag);
      float4 bv = *(const float4*)(W + (size_t)(k0 + bk) * 128 + bg);
      __syncthreads();
      As[ag + 0][ar] = av.x;
      As[ag + 1][ar] = av.y;
      As[ag + 2][ar] = av.z;
      As[ag + 3][ar] = av.w;
      *(float4*)(&Bs[bk][bg]) = bv;
      __syncthreads();
#pragma unroll
      for (int k = 0; k < 8; ++k) {
        float a[8], b[8];
        *(float4*)(a)     = *(const float4*)(&As[k][ty * 8]);
        *(float4*)(a + 4) = *(const float4*)(&As[k][ty * 8 + 4]);
        *(float4*)(b)     = *(const float4*)(&Bs[k][tx * 8]);
        *(float4*)(b + 4) = *(const float4*)(&Bs[k][tx * 8 + 4]);
#pragma unroll
        for (int i = 0; i < 8; ++i)
#pragma unroll
          for (int j = 0; j < 8; ++j) acc[i][j] = fmaf(a[i], b[j], acc[i][j]);
      }
    }
  }

#pragma unroll
  for (int i = 0; i < 8; ++i) {
    int r = row0 + ty * 8 + i;
    if (r >= M) continue;
    float* dstp = out + (size_t)r * 128;
#pragma unroll
    for (int jv = 0; jv < 2; ++jv) {
      int c = tx * 8 + jv * 4;
      float4 v;
      v.x = acc[i][jv * 4 + 0] + ba[c + 0] + bb[c + 0];
      v.y = acc[i][jv * 4 + 1] + ba[c + 1] + bb[c + 1];
      v.z = acc[i][jv * 4 + 2] + ba[c + 2] + bb[c + 2];
      v.w = acc[i][jv * 4 + 3] + ba[c + 3] + bb[c + 3];
      v.x = (v.x > 0.f) ? v.x : 0.01f * v.x;
      v.y = (v.y > 0.f) ? v.y : 0.01f * v.y;
      v.z = (v.z > 0.f) ? v.z : 0.01f * v.z;
      v.w = (v.w > 0.f) ? v.w : 0.01f * v.w;
      *(float4*)(dstp + c) = v;
    }
  }
}

// ---------------------------------------------------------------------------
// FC head: y = h @ fcw + fcb   ([N,128]x[128,64]); one wave per row.
// ---------------------------------------------------------------------------
__global__ __launch_bounds__(256) void k_fc(const float* __restrict__ h,
                                            const float* __restrict__ fcw,
                                            const float* __restrict__ fcb,
                                            float* __restrict__ y, int n) {
  __shared__ float ws[128 * 64];
  for (int t = threadIdx.x; t < 128 * 64; t += 256) ws[t] = fcw[t];
  __syncthreads();
  const int wave = threadIdx.x >> 6;
  const int lane = threadIdx.x & 63;
  const int i = blockIdx.x * 4 + wave;
  if (i >= n) return;
  const float* hr = h + (size_t)i * 128;
  float acc = fcb[lane];
#pragma unroll 8
  for (int k4 = 0; k4 < 32; ++k4) {
    float4 hv = *(const float4*)(hr + k4 * 4);
    acc = fmaf(hv.x, ws[(k4 * 4 + 0) * 64 + lane], acc);
    acc = fmaf(hv.y, ws[(k4 * 4 + 1) * 64 + lane], acc);
    acc = fmaf(hv.z, ws[(k4 * 4 + 2) * 64 + lane], acc);
    acc = fmaf(hv.w, ws[(k4 * 4 + 3) * 64 + lane], acc);
  }
  y[(size_t)i * 64 + lane] = acc;
}

// ---------------------------------------------------------------------------

extern "C" void kernel_launch(void* const* d_in, const int* in_sizes, int n_in,
                              void* d_out, int out_size, void* d_ws, size_t ws_size,
                              hipStream_t stream) {
  const float* X  = (const float*)d_in[0];
  const int* ei   = (const int*)d_in[1];       // int32 per harness convention
  const float* gw1 = (const float*)d_in[3];
  const float* gb1 = (const float*)d_in[4];
  const float* lw1 = (const float*)d_in[5];
  const float* lb1 = (const float*)d_in[6];
  const float* gw2 = (const float*)d_in[7];
  const float* gb2 = (const float*)d_in[8];
  const float* lw2 = (const float*)d_in[9];
  const float* lb2 = (const float*)d_in[10];
  const float* gw3 = (const float*)d_in[11];
  const float* gb3 = (const float*)d_in[12];
  const float* lw3 = (const float*)d_in[13];
  const float* lb3 = (const float*)d_in[14];
  const float* fcw = (const float*)d_in[15];
  const float* fcb = (const float*)d_in[16];

  const int n = in_sizes[0] / 128;
  const int E = in_sizes[1] / 2;
  const int tot = E + n;

  char* ws = (char*)d_ws;
  size_t off = 0;
  auto alloc = [&](size_t bytes) -> void* {
    void* p = ws + off;
    off = (off + bytes + 255) & ~(size_t)255;
    return p;
  };
  const int gN = (n + 255) / 256;      // also = #scan blocks (<=512 required)
  int* deg     = (int*)alloc((size_t)n * 4);
  float* dis   = (float*)alloc((size_t)n * 4);
  int* rowptr  = (int*)alloc((size_t)(n + 1) * 4);
  int* fillctr = (int*)alloc((size_t)n * 4);
  int* partial = (int*)alloc((size_t)gN * 4);
  int* poff    = (int*)alloc((size_t)gN * 4);
  int* col     = (int*)alloc((size_t)tot * 4);
  float* SX    = (float*)alloc((size_t)n * 128 * 4);   // total ~59.7 MB

  float* outh = (float*)d_out;                 // [n,128] final h (also h ping)
  float* outy = outh + (size_t)n * 128;        // [n,64]  final y

  const int gE = (E + 255) / 256;
  const int gT = (tot + 255) / 256;
  const int gM = (n + BM - 1) / BM;
  const int gW = (n + 3) / 4;

  // ---- graph preprocessing (deterministic; rebuilt every call) ----
  k_init_deg<<<gN, 256, 0, stream>>>(deg, n);
  k_count<<<gE, 256, 0, stream>>>(ei, deg, E);
  k_partial<<<gN, 256, 0, stream>>>(deg, partial, n);
  k_scanp<<<1, 512, 0, stream>>>(partial, poff, gN, rowptr, n, tot);
  k_write<<<gN, 256, 0, stream>>>(deg, poff, rowptr, fillctr, dis, n);
  k_fill<<<gT, 256, 0, stream>>>(ei, fillctr, col, E, n);

  // ---- layer 1: SX = S@X ; h1 = lrelu(SX@gw1 + X@lw1 + b) -> outh ----
  k_spmv<<<gW, 256, 0, stream>>>(rowptr, col, dis, X, SX, n);
  k_gemm2<<<gM, 256, 0, stream>>>(SX, X, gw1, lw1, gb1, lb1, outh, n);
  // ---- layer 2 (in-place on outh) ----
  k_spmv<<<gW, 256, 0, stream>>>(rowptr, col, dis, outh, SX, n);
  k_gemm2<<<gM, 256, 0, stream>>>(SX, outh, gw2, lw2, gb2, lb2, outh, n);
  // ---- layer 3 (in-place on outh) ----
  k_spmv<<<gW, 256, 0, stream>>>(rowptr, col, dis, outh, SX, n);
  k_gemm2<<<gM, 256, 0, stream>>>(SX, outh, gw3, lw3, gb3, lb3, outh, n);
  // ---- FC head ----
  k_fc<<<gW, 256, 0, stream>>>(outh, fcw, fcb, outy, n);
}

// Round 4
// 848.345 us; speedup vs baseline: 1.5903x; 1.3273x over previous
//
#include <hip/hip_runtime.h>
#include <cstdint>
#include <cstddef>

// ---------------------------------------------------------------------------
// GCN 3-layer + FC head. Round 4: bf16 features + MFMA GEMM (no LDS),
// bf16 spmv gather (halves the dominant gather traffic).
// ---------------------------------------------------------------------------

typedef __attribute__((ext_vector_type(4))) float f32x4;
typedef __attribute__((ext_vector_type(8))) short bf16x8;
typedef unsigned short u16;

__device__ __forceinline__ float bf2f(unsigned int u) {
  union { unsigned int i; float f; } v;
  v.i = u << 16;
  return v.f;
}
__device__ __forceinline__ u16 f2bf(float f) {
  union { float f; unsigned int i; } v;
  v.f = f;
  unsigned int i = v.i;
  return (u16)((i + 0x7FFFu + ((i >> 16) & 1u)) >> 16);  // RNE
}

// ---------------- graph preprocessing ----------------

__global__ __launch_bounds__(256) void k_init_deg(int* __restrict__ deg, int n) {
  int i = blockIdx.x * 256 + threadIdx.x;
  if (i < n) deg[i] = 1;              // self-loop
}

__global__ __launch_bounds__(256) void k_count(const int* __restrict__ ei,
                                               int* __restrict__ deg, int E) {
  int e = blockIdx.x * 256 + threadIdx.x;
  if (e < E) atomicAdd(&deg[ei[E + e]], 1);   // dst half
}

__global__ __launch_bounds__(256) void k_partial(const int* __restrict__ deg,
                                                 int* __restrict__ partial, int n) {
  __shared__ int sm[256];
  int t = threadIdx.x;
  int i = blockIdx.x * 256 + t;
  sm[t] = (i < n) ? deg[i] : 0;
  __syncthreads();
#pragma unroll
  for (int off = 128; off > 0; off >>= 1) {
    if (t < off) sm[t] += sm[t + off];
    __syncthreads();
  }
  if (t == 0) partial[blockIdx.x] = sm[0];
}

__global__ __launch_bounds__(512) void k_scanp(const int* __restrict__ partial,
                                               int* __restrict__ poff, int nb,
                                               int* __restrict__ rowptr, int n,
                                               int total) {
  __shared__ int sm[512];
  int t = threadIdx.x;
  sm[t] = (t < nb) ? partial[t] : 0;
  __syncthreads();
  for (int off = 1; off < 512; off <<= 1) {
    int v = (t >= off) ? sm[t - off] : 0;
    __syncthreads();
    sm[t] += v;
    __syncthreads();
  }
  if (t < nb) poff[t] = (t == 0) ? 0 : sm[t - 1];
  if (t == 0) rowptr[n] = total;
}

__global__ __launch_bounds__(256) void k_write(const int* __restrict__ deg,
                                               const int* __restrict__ poff,
                                               int* __restrict__ rowptr,
                                               int* __restrict__ fillctr,
                                               float* __restrict__ dis, int n) {
  __shared__ int sm[256];
  int t = threadIdx.x;
  int i = blockIdx.x * 256 + t;
  int v = (i < n) ? deg[i] : 0;
  sm[t] = v;
  __syncthreads();
  for (int off = 1; off < 256; off <<= 1) {
    int u = (t >= off) ? sm[t - off] : 0;
    __syncthreads();
    sm[t] += u;
    __syncthreads();
  }
  if (i < n) {
    int excl = poff[blockIdx.x] + sm[t] - v;
    rowptr[i] = excl;
    fillctr[i] = excl;
    dis[i] = rsqrtf((float)v);        // deg >= 1 always
  }
}

__global__ __launch_bounds__(256) void k_fill(const int* __restrict__ ei,
                                              int* __restrict__ fillctr,
                                              int* __restrict__ col,
                                              int E, int n) {
  int e = blockIdx.x * 256 + threadIdx.x;
  int total = E + n;
  if (e >= total) return;
  int s, d;
  if (e < E) {
    s = ei[e];
    d = ei[E + e];
  } else {
    s = e - E;  // self-loop
    d = s;
  }
  int pos = atomicAdd(&fillctr[d], 1);
  col[pos] = s;
}

// ---------------- dtype conversion ----------------

// X fp32 -> bf16, 8 elems/thread
__global__ __launch_bounds__(256) void k_cvt(const float* __restrict__ src,
                                             u16* __restrict__ dst, int total8) {
  int i = blockIdx.x * 256 + threadIdx.x;
  if (i >= total8) return;
  size_t b = (size_t)i * 8;
  float4 a0 = *(const float4*)(src + b);
  float4 a1 = *(const float4*)(src + b + 4);
  u16 o[8] = {f2bf(a0.x), f2bf(a0.y), f2bf(a0.z), f2bf(a0.w),
              f2bf(a1.x), f2bf(a1.y), f2bf(a1.z), f2bf(a1.w)};
  *(ulonglong2*)(dst + b) = *(ulonglong2*)o;
}

// transpose+convert 6 weight matrices [128,128]: WT[z][n][k] = bf16(W[k][n])
__global__ __launch_bounds__(128) void k_wt(const float* __restrict__ w0,
                                            const float* __restrict__ w1,
                                            const float* __restrict__ w2,
                                            const float* __restrict__ w3,
                                            const float* __restrict__ w4,
                                            const float* __restrict__ w5,
                                            u16* __restrict__ dst) {
  const float* Ws[6] = {w0, w1, w2, w3, w4, w5};
  const float* W = Ws[blockIdx.y];
  int nr = blockIdx.x;           // output row (= col of W)
  int k = threadIdx.x;
  dst[(size_t)blockIdx.y * 16384 + nr * 128 + k] = f2bf(W[k * 128 + nr]);
}

// combined biases: bias[L*128+c] = gb[c] + lb[c]
__global__ __launch_bounds__(256) void k_bias(const float* __restrict__ g1,
                                              const float* __restrict__ l1,
                                              const float* __restrict__ g2,
                                              const float* __restrict__ l2,
                                              const float* __restrict__ g3,
                                              const float* __restrict__ l3,
                                              float* __restrict__ bias) {
  int t = blockIdx.x * 256 + threadIdx.x;
  if (t >= 384) return;
  const float* gs[3] = {g1, g2, g3};
  const float* ls[3] = {l1, l2, l3};
  bias[t] = gs[t >> 7][t & 127] + ls[t >> 7][t & 127];
}

// ---------------------------------------------------------------------------
// SXb[i] = bf16( dis[i] * sum_j dis[col[j]] * Xb[col[j], :] )
// one wave/node, uint (2xbf16) per lane, fp32 accum, 2-edge unroll.
// ---------------------------------------------------------------------------
__global__ __launch_bounds__(256) void k_spmv_bf(const int* __restrict__ rowptr,
                                                 const int* __restrict__ col,
                                                 const float* __restrict__ dis,
                                                 const u16* __restrict__ Xb,
                                                 u16* __restrict__ SXb, int n) {
  const int wave = threadIdx.x >> 6;
  const int lane = threadIdx.x & 63;
  const int i = blockIdx.x * 4 + wave;
  if (i >= n) return;
  int j = rowptr[i];
  const int end = rowptr[i + 1];
  float ax = 0.f, ay = 0.f;
  for (; j + 1 < end; j += 2) {
    int c0 = col[j], c1 = col[j + 1];
    float w0 = dis[c0], w1 = dis[c1];
    unsigned int q0 = *(const unsigned int*)(Xb + (size_t)c0 * 128 + lane * 2);
    unsigned int q1 = *(const unsigned int*)(Xb + (size_t)c1 * 128 + lane * 2);
    ax = fmaf(bf2f(q0 & 0xffffu), w0, ax);
    ay = fmaf(bf2f(q0 >> 16), w0, ay);
    ax = fmaf(bf2f(q1 & 0xffffu), w1, ax);
    ay = fmaf(bf2f(q1 >> 16), w1, ay);
  }
  if (j < end) {
    int c0 = col[j];
    float w0 = dis[c0];
    unsigned int q0 = *(const unsigned int*)(Xb + (size_t)c0 * 128 + lane * 2);
    ax = fmaf(bf2f(q0 & 0xffffu), w0, ax);
    ay = fmaf(bf2f(q0 >> 16), w0, ay);
  }
  float di = dis[i];
  ax *= di;
  ay *= di;
  unsigned int o = (unsigned int)f2bf(ax) | ((unsigned int)f2bf(ay) << 16);
  *(unsigned int*)(SXb + (size_t)i * 128 + lane * 2) = o;
}

// ---------------------------------------------------------------------------
// MFMA fused layer:  out = lrelu( A0@W0 + A1@W1 + bias ),  all [*,128]x[128,128]
// A0,A1 bf16 row-major; W0T,W1T bf16 [n][k] (pre-transposed). No LDS.
// Block: 256 thr = 4 waves; wave w owns rows row0+w*32..+32; acc 2x8 f32x4.
// Fragment mapping (gfx950 16x16x32): A: lane l -> row l&15, k (l>>4)*8+e.
//                                     B: lane l -> col l&15, k (l>>4)*8+e.
//                                     D: lane l -> col l&15, row (l>>4)*4+e.
// outb!=null: store bf16. outf!=null: store fp32 (layer 3).
// ---------------------------------------------------------------------------
__global__ __launch_bounds__(256) void k_mfma(const u16* __restrict__ A0,
                                              const u16* __restrict__ A1,
                                              const u16* __restrict__ W0T,
                                              const u16* __restrict__ W1T,
                                              const float* __restrict__ bias,
                                              u16* __restrict__ outb,
                                              float* __restrict__ outf, int M) {
  const int lane = threadIdx.x & 63;
  const int wv = threadIdx.x >> 6;
  const int row0 = blockIdx.x * 128 + wv * 32;
  const int r = lane & 15;
  const int kg = lane >> 4;

  f32x4 acc[2][8];
#pragma unroll
  for (int a = 0; a < 2; ++a)
#pragma unroll
    for (int j = 0; j < 8; ++j) acc[a][j] = (f32x4){0.f, 0.f, 0.f, 0.f};

  const int ra0 = min(row0 + r, M - 1);
  const int ra1 = min(row0 + 16 + r, M - 1);

#pragma unroll
  for (int p = 0; p < 2; ++p) {
    const u16* A = p ? A1 : A0;
    const u16* WT = p ? W1T : W0T;
#pragma unroll
    for (int kk = 0; kk < 4; ++kk) {
      const int k0 = kk * 32 + kg * 8;
      bf16x8 a0 = *(const bf16x8*)(A + (size_t)ra0 * 128 + k0);
      bf16x8 a1 = *(const bf16x8*)(A + (size_t)ra1 * 128 + k0);
#pragma unroll
      for (int j = 0; j < 8; ++j) {
        bf16x8 b = *(const bf16x8*)(WT + (size_t)(j * 16 + r) * 128 + k0);
        acc[0][j] = __builtin_amdgcn_mfma_f32_16x16x32_bf16(a0, b, acc[0][j], 0, 0, 0);
        acc[1][j] = __builtin_amdgcn_mfma_f32_16x16x32_bf16(a1, b, acc[1][j], 0, 0, 0);
      }
    }
  }

#pragma unroll
  for (int rf = 0; rf < 2; ++rf)
#pragma unroll
    for (int e = 0; e < 4; ++e) {
      const int row = row0 + rf * 16 + kg * 4 + e;
      if (row >= M) continue;
#pragma unroll
      for (int j = 0; j < 8; ++j) {
        const int c = j * 16 + r;
        float v = acc[rf][j][e] + bias[c];
        v = (v > 0.f) ? v : 0.01f * v;
        if (outf) outf[(size_t)row * 128 + c] = v;
        else outb[(size_t)row * 128 + c] = f2bf(v);
      }
    }
}

// ---------------------------------------------------------------------------
// FC head: y = h @ fcw + fcb   ([N,128]x[128,64] fp32); one wave per row.
// ---------------------------------------------------------------------------
__global__ __launch_bounds__(256) void k_fc(const float* __restrict__ h,
                                            const float* __restrict__ fcw,
                                            const float* __restrict__ fcb,
                                            float* __restrict__ y, int n) {
  __shared__ float ws[128 * 64];
  for (int t = threadIdx.x; t < 128 * 64; t += 256) ws[t] = fcw[t];
  __syncthreads();
  const int wave = threadIdx.x >> 6;
  const int lane = threadIdx.x & 63;
  const int i = blockIdx.x * 4 + wave;
  if (i >= n) return;
  const float* hr = h + (size_t)i * 128;
  float acc = fcb[lane];
#pragma unroll 8
  for (int k4 = 0; k4 < 32; ++k4) {
    float4 hv = *(const float4*)(hr + k4 * 4);
    acc = fmaf(hv.x, ws[(k4 * 4 + 0) * 64 + lane], acc);
    acc = fmaf(hv.y, ws[(k4 * 4 + 1) * 64 + lane], acc);
    acc = fmaf(hv.z, ws[(k4 * 4 + 2) * 64 + lane], acc);
    acc = fmaf(hv.w, ws[(k4 * 4 + 3) * 64 + lane], acc);
  }
  y[(size_t)i * 64 + lane] = acc;
}

// ---------------------------------------------------------------------------

extern "C" void kernel_launch(void* const* d_in, const int* in_sizes, int n_in,
                              void* d_out, int out_size, void* d_ws, size_t ws_size,
                              hipStream_t stream) {
  const float* X  = (const float*)d_in[0];
  const int* ei   = (const int*)d_in[1];
  const float* gw1 = (const float*)d_in[3];
  const float* gb1 = (const float*)d_in[4];
  const float* lw1 = (const float*)d_in[5];
  const float* lb1 = (const float*)d_in[6];
  const float* gw2 = (const float*)d_in[7];
  const float* gb2 = (const float*)d_in[8];
  const float* lw2 = (const float*)d_in[9];
  const float* lb2 = (const float*)d_in[10];
  const float* gw3 = (const float*)d_in[11];
  const float* gb3 = (const float*)d_in[12];
  const float* lw3 = (const float*)d_in[13];
  const float* lb3 = (const float*)d_in[14];
  const float* fcw = (const float*)d_in[15];
  const float* fcb = (const float*)d_in[16];

  const int n = in_sizes[0] / 128;
  const int E = in_sizes[1] / 2;
  const int tot = E + n;

  char* ws = (char*)d_ws;
  size_t off = 0;
  auto alloc = [&](size_t bytes) -> void* {
    void* p = ws + off;
    off = (off + bytes + 255) & ~(size_t)255;
    return p;
  };
  const int gN = (n + 255) / 256;   // #scan blocks (<=512 required)
  int* deg     = (int*)alloc((size_t)n * 4);
  float* dis   = (float*)alloc((size_t)n * 4);
  int* rowptr  = (int*)alloc((size_t)(n + 1) * 4);
  int* fillctr = (int*)alloc((size_t)n * 4);
  int* partial = (int*)alloc((size_t)gN * 4);
  int* poff    = (int*)alloc((size_t)gN * 4);
  int* col     = (int*)alloc((size_t)tot * 4);
  u16* Xb      = (u16*)alloc((size_t)n * 128 * 2);
  u16* SXb     = (u16*)alloc((size_t)n * 128 * 2);
  u16* WT      = (u16*)alloc((size_t)6 * 16384 * 2);
  float* bias  = (float*)alloc(384 * 4);          // total ~59.9 MB

  float* outh = (float*)d_out;                 // [n,128] final h fp32
  float* outy = outh + (size_t)n * 128;        // [n,64]  final y fp32
  u16* hb = (u16*)outy;  // bf16 h ping-buffer in y-region (n*256 B, exact fit);
                         // overwritten by k_fc at the very end of every call.

  const int gE = (E + 255) / 256;
  const int gT = (tot + 255) / 256;
  const int gM = (n + 127) / 128;
  const int gW = (n + 3) / 4;
  const int g8 = (n * 128 / 8 + 255) / 256;

  // ---- graph preprocessing ----
  k_init_deg<<<gN, 256, 0, stream>>>(deg, n);
  k_count<<<gE, 256, 0, stream>>>(ei, deg, E);
  k_partial<<<gN, 256, 0, stream>>>(deg, partial, n);
  k_scanp<<<1, 512, 0, stream>>>(partial, poff, gN, rowptr, n, tot);
  k_write<<<gN, 256, 0, stream>>>(deg, poff, rowptr, fillctr, dis, n);
  k_fill<<<gT, 256, 0, stream>>>(ei, fillctr, col, E, n);

  // ---- dtype prep ----
  k_cvt<<<g8, 256, 0, stream>>>(X, Xb, n * 128 / 8);
  k_wt<<<dim3(128, 6), 128, 0, stream>>>(gw1, lw1, gw2, lw2, gw3, lw3, WT);
  k_bias<<<2, 256, 0, stream>>>(gb1, lb1, gb2, lb2, gb3, lb3, bias);

  // ---- layer 1 ----
  k_spmv_bf<<<gW, 256, 0, stream>>>(rowptr, col, dis, Xb, SXb, n);
  k_mfma<<<gM, 256, 0, stream>>>(SXb, Xb, WT, WT + 16384, bias, hb, nullptr, n);
  // ---- layer 2 (hb in-place: block writes only its own rows, post-loop) ----
  k_spmv_bf<<<gW, 256, 0, stream>>>(rowptr, col, dis, hb, SXb, n);
  k_mfma<<<gM, 256, 0, stream>>>(SXb, hb, WT + 2 * 16384, WT + 3 * 16384,
                                 bias + 128, hb, nullptr, n);
  // ---- layer 3: fp32 h -> d_out ----
  k_spmv_bf<<<gW, 256, 0, stream>>>(rowptr, col, dis, hb, SXb, n);
  k_mfma<<<gM, 256, 0, stream>>>(SXb, hb, WT + 4 * 16384, WT + 5 * 16384,
                                 bias + 256, nullptr, outh, n);
  // ---- FC head (reads fp32 h, writes y over hb) ----
  k_fc<<<gW, 256, 0, stream>>>(outh, fcw, fcb, outy, n);
}